// Round 2
// 962.079 us; speedup vs baseline: 1.1799x; 1.1799x over previous
//
#include <hip/hip_runtime.h>
#include <hip/hip_bf16.h>
#include <stdint.h>

typedef __attribute__((ext_vector_type(8))) short s16x8;
typedef __attribute__((ext_vector_type(4))) float f32x4;

__device__ __forceinline__ unsigned short f2bf(float f) {
    unsigned int u = __float_as_uint(f);
    u += 0x7fffu + ((u >> 16) & 1u);   // round-to-nearest-even
    return (unsigned short)(u >> 16);
}

__device__ __forceinline__ void load16_lds(const unsigned short* g, unsigned short* l) {
    __builtin_amdgcn_global_load_lds(
        (const __attribute__((address_space(1))) unsigned int*)g,
        (__attribute__((address_space(3))) unsigned int*)l,
        16, 0, 0);
}

// ---------------- fused fp32 -> bf16 convert over 3 arrays (float4 units) ----------------
__global__ __launch_bounds__(256) void cvt3(
    const float* __restrict__ a, unsigned short* __restrict__ da, int na,
    const float* __restrict__ b, unsigned short* __restrict__ db, int nb,
    const float* __restrict__ c, unsigned short* __restrict__ dc, int nc)
{
    const int total = na + nb + nc;
    for (int i = blockIdx.x * 256 + threadIdx.x; i < total; i += gridDim.x * 256) {
        const float* s; unsigned short* d; int j = i;
        if (j < na)            { s = a; d = da; }
        else if (j < na + nb)  { s = b; d = db; j -= na; }
        else                   { s = c; d = dc; j -= na + nb; }
        float4 v = ((const float4*)s)[j];
        ushort4 o;
        o.x = f2bf(v.x); o.y = f2bf(v.y); o.z = f2bf(v.z); o.w = f2bf(v.w);
        ((ushort4*)d)[j] = o;
    }
}

__global__ __launch_bounds__(256) void recip_k(float* __restrict__ p, int n) {
    int i = blockIdx.x * 256 + threadIdx.x;
    if (i < n) p[i] = 1.0f / p[i];
}

// =====================================================================================
// 256x256 tile, 512 threads = 8 waves (2M x 4N). K consumed in 32-wide K-halves (KH).
// 4-slot LDS ring (4 x 32KB = 128KB), 3-deep prefetch, counted s_waitcnt vmcnt(8)
// at phase boundaries (T3+T4), setprio around MFMA cluster (T5).
// Each wave owns a 128x64 output tile: acc[8][4] of 16x16x32 fragments.
// MODE 0: bf16 out + bias (projections)
// MODE 2: bf16 out = exp(acc*scale), atomicAdd row sums (S~)
// MODE 3: f32 out = acc * rowinv[row]  (O)
//
// vmcnt ledger (per thread, 4 loads per KH):
//   prologue: KH0,KH1,KH2 in flight (12).
//   phase j: wait vmcnt(8) retires KH_j; barrier; stage KH_{j+3} into slot (j-1)&3
//   (all waves' reads of slot j-1 drained before their phase-j barrier arrival).
//   tail: j+3==NKH -> vmcnt(8); j+2==NKH -> vmcnt(4); j+1==NKH -> vmcnt(0).
// =====================================================================================
template <int MODE>
__global__ __launch_bounds__(512, 2) void gemm256(
    const unsigned short* __restrict__ A, const unsigned short* __restrict__ B,
    void* __restrict__ Cv, const float* __restrict__ bias,
    float* __restrict__ rowsum, const float* __restrict__ rowinv, float scale,
    int M, int N, int K,
    long long strideA, long long strideB, long long strideC)
{
    // 4 KH slots: each slot = A[256][32] (8192 sh) + B[256][32] (8192 sh) = 32 KiB
    __shared__ unsigned short sh[65536];   // 128 KiB

    const int batch = blockIdx.y;
    A += (long long)batch * strideA;
    B += (long long)batch * strideB;

    const int ntn = N >> 8;
    const int tm = blockIdx.x / ntn;
    const int tn = blockIdx.x % ntn;

    const int tid  = threadIdx.x;
    const int wave = tid >> 6;
    const int lane = tid & 63;
    const int quad = lane >> 4;
    const int l16  = lane & 15;
    const int wm   = wave >> 2;    // 0..1 (M half)
    const int wn   = wave & 3;     // 0..3 (N quarter)

    // staging: per KH, 4 units [A-lo, A-hi, B-lo, B-hi], each [128][32] row-major.
    // global_load_lds writes LDS at (uniform base) + lane*16B; with per-lane source
    // row = wave*16 + lane/4, col = (lane&3)*8 this lands exactly row-major.
    const int srow = (wave << 4) + (lane >> 2);          // 0..127
    const int scol = (lane & 3) << 3;                    // 0,8,16,24
    const unsigned short* gA0 = A + (long long)(tm * 256 +       srow) * K + scol;
    const unsigned short* gA1 = A + (long long)(tm * 256 + 128 + srow) * K + scol;
    const unsigned short* gB0 = B + (long long)(tn * 256 +       srow) * K + scol;
    const unsigned short* gB1 = B + (long long)(tn * 256 + 128 + srow) * K + scol;
    const int sdst = wave * 512;                         // wave-uniform short offset in unit

    const int NKH = K >> 5;                              // 32-wide K-halves (>=3 always here)

    // fragment read offsets (shorts), slot-relative. A-frag: row=l16 (+16m), k=quad*8.
    const int aoff =        wm * 4096 + l16 * 32 + quad * 8;
    const int boff = 8192 + wn * 2048 + l16 * 32 + quad * 8;

    f32x4 acc[8][4] = {};

    // prologue: stage KH 0,1,2
    for (int p = 0; p < 3; ++p) {
        unsigned short* sb = sh + p * 16384;
        const int kof = p * 32;
        load16_lds(gA0 + kof, sb +         sdst);
        load16_lds(gA1 + kof, sb +  4096 + sdst);
        load16_lds(gB0 + kof, sb +  8192 + sdst);
        load16_lds(gB1 + kof, sb + 12288 + sdst);
    }

    for (int j = 0; j < NKH; ++j) {
        __builtin_amdgcn_sched_barrier(0);
        if (j + 3 <= NKH)      { asm volatile("s_waitcnt vmcnt(8) lgkmcnt(0)" ::: "memory"); }
        else if (j + 2 == NKH) { asm volatile("s_waitcnt vmcnt(4) lgkmcnt(0)" ::: "memory"); }
        else                   { asm volatile("s_waitcnt vmcnt(0) lgkmcnt(0)" ::: "memory"); }
        __builtin_amdgcn_s_barrier();
        __builtin_amdgcn_sched_barrier(0);

        // stage KH j+3 into slot (j+3)&3 == (j-1)&3 (freed by the barrier above)
        if (j + 3 < NKH) {
            unsigned short* sb = sh + ((j + 3) & 3) * 16384;
            const int kof = (j + 3) * 32;
            load16_lds(gA0 + kof, sb +         sdst);
            load16_lds(gA1 + kof, sb +  4096 + sdst);
            load16_lds(gB0 + kof, sb +  8192 + sdst);
            load16_lds(gB1 + kof, sb + 12288 + sdst);
        }

        const unsigned short* sa  = sh + (j & 3) * 16384 + aoff;
        const unsigned short* sbb = sh + (j & 3) * 16384 + boff;
        s16x8 af[8], bfr[4];
#pragma unroll
        for (int n = 0; n < 4; ++n) bfr[n] = *(const s16x8*)(sbb + n * 512);
#pragma unroll
        for (int m = 0; m < 8; ++m) af[m] = *(const s16x8*)(sa + m * 512);

        __builtin_amdgcn_s_setprio(1);
#pragma unroll
        for (int m = 0; m < 8; ++m)
#pragma unroll
            for (int n = 0; n < 4; ++n)
                acc[m][n] = __builtin_amdgcn_mfma_f32_16x16x32_bf16(af[m], bfr[n], acc[m][n], 0, 0, 0);
        __builtin_amdgcn_s_setprio(0);
    }
    // last phase waited vmcnt(0) lgkmcnt(0): clean entering the epilogue.

    // C/D layout: col = l16, row = quad*4 + reg
    if (MODE == 0) {
        unsigned short* C = (unsigned short*)Cv + (long long)batch * strideC;
#pragma unroll
        for (int m = 0; m < 8; ++m) {
            const int m0 = tm * 256 + wm * 128 + m * 16 + quad * 4;
#pragma unroll
            for (int n = 0; n < 4; ++n) {
                const int c = tn * 256 + wn * 64 + n * 16 + l16;
                const float bv = bias[c];
#pragma unroll
                for (int r = 0; r < 4; ++r)
                    C[(long long)(m0 + r) * N + c] = f2bf(acc[m][n][r] + bv);
            }
        }
    } else if (MODE == 2) {
        unsigned short* C = (unsigned short*)Cv + (long long)batch * strideC;
        float psum[8][4];
#pragma unroll
        for (int m = 0; m < 8; ++m)
#pragma unroll
            for (int r = 0; r < 4; ++r) psum[m][r] = 0.0f;
#pragma unroll
        for (int m = 0; m < 8; ++m) {
            const int m0 = tm * 256 + wm * 128 + m * 16 + quad * 4;
#pragma unroll
            for (int n = 0; n < 4; ++n) {
                const int c = tn * 256 + wn * 64 + n * 16 + l16;
#pragma unroll
                for (int r = 0; r < 4; ++r) {
                    float e = __expf(acc[m][n][r] * scale);
                    C[(long long)(m0 + r) * N + c] = f2bf(e);
                    psum[m][r] += e;
                }
            }
        }
        float* rs = rowsum + (long long)batch * 2048;
#pragma unroll
        for (int m = 0; m < 8; ++m) {
            const int m0 = tm * 256 + wm * 128 + m * 16 + quad * 4;
#pragma unroll
            for (int r = 0; r < 4; ++r) {
                float v = psum[m][r];
                v += __shfl_xor(v, 1);
                v += __shfl_xor(v, 2);
                v += __shfl_xor(v, 4);
                v += __shfl_xor(v, 8);
                if (l16 == 0) atomicAdd(&rs[m0 + r], v);
            }
        }
    } else { // MODE 3
        float* C = (float*)Cv + (long long)batch * strideC;
        const float* ri = rowinv + (long long)batch * 2048;
#pragma unroll
        for (int m = 0; m < 8; ++m) {
            const int m0 = tm * 256 + wm * 128 + m * 16 + quad * 4;
            const float4 inv4 = *(const float4*)&ri[m0];
#pragma unroll
            for (int n = 0; n < 4; ++n) {
                const int c = tn * 256 + wn * 64 + n * 16 + l16;
                C[(long long)(m0 + 0) * N + c] = acc[m][n][0] * inv4.x;
                C[(long long)(m0 + 1) * N + c] = acc[m][n][1] * inv4.y;
                C[(long long)(m0 + 2) * N + c] = acc[m][n][2] * inv4.z;
                C[(long long)(m0 + 3) * N + c] = acc[m][n][3] * inv4.w;
            }
        }
    }
}

// ---------------- OLD 128x128 kernel, retained ONLY for the fused v-proj transpose ----
template <int MODE>
__global__ __launch_bounds__(256) void gemm_bt(
    const unsigned short* __restrict__ A, const unsigned short* __restrict__ B,
    void* __restrict__ Cv, const float* __restrict__ bias,
    float* __restrict__ rowsum, const float* __restrict__ rowinv, float scale,
    int M, int N, int K,
    long long strideA, long long strideB, long long strideC)
{
    __shared__ unsigned short sh[8192];       // 16 KB: lA (4096) + lB (4096)
    unsigned short* lA = sh;
    unsigned short* lB = sh + 4096;

    const int batch = blockIdx.y;
    A += (long long)batch * strideA;
    B += (long long)batch * strideB;

    const int ntn = N >> 7;
    const int tm = blockIdx.x / ntn;
    const int tn = blockIdx.x % ntn;

    const int tid = threadIdx.x;
    const int wave = tid >> 6;
    const int lane = tid & 63;
    const int quad = lane >> 4;
    const int l16 = lane & 15;

    const int col = (lane & 3) * 8;
    const int idx0 = (wave * 2 + 0) * 64 + lane;
    const int idx1 = (wave * 2 + 1) * 64 + lane;
    const unsigned short* gA0 = A + (long long)(tm * 128 + (idx0 >> 2)) * K + col;
    const unsigned short* gA1 = A + (long long)(tm * 128 + (idx1 >> 2)) * K + col;
    const unsigned short* gB0 = B + (long long)(tn * 128 + (idx0 >> 2)) * K + col;
    const unsigned short* gB1 = B + (long long)(tn * 128 + (idx1 >> 2)) * K + col;
    unsigned short* dA0 = lA + (wave * 2 + 0) * 512;
    unsigned short* dA1 = lA + (wave * 2 + 1) * 512;
    unsigned short* dB0 = lB + (wave * 2 + 0) * 512;
    unsigned short* dB1 = lB + (wave * 2 + 1) * 512;

    const int wm = (wave >> 1) * 64;
    const int wn = (wave & 1) * 64;

    f32x4 acc[4][4] = {};

    for (int k0 = 0; k0 < K; k0 += 32) {
        __syncthreads();
        load16_lds(gA0, dA0);
        load16_lds(gA1, dA1);
        load16_lds(gB0, dB0);
        load16_lds(gB1, dB1);
        gA0 += 32; gA1 += 32; gB0 += 32; gB1 += 32;
        __syncthreads();

        s16x8 af[4], bfr[4];
#pragma unroll
        for (int i = 0; i < 4; ++i)
            af[i] = *(const s16x8*)&lA[(wm + i * 16 + l16) * 32 + quad * 8];
#pragma unroll
        for (int j = 0; j < 4; ++j)
            bfr[j] = *(const s16x8*)&lB[(wn + j * 16 + l16) * 32 + quad * 8];
#pragma unroll
        for (int i = 0; i < 4; ++i)
#pragma unroll
            for (int j = 0; j < 4; ++j)
                acc[i][j] = __builtin_amdgcn_mfma_f32_16x16x32_bf16(af[i], bfr[j], acc[i][j], 0, 0, 0);
    }

    if (MODE == 0) {
        unsigned short* C = (unsigned short*)Cv + (long long)batch * strideC;
#pragma unroll
        for (int i = 0; i < 4; ++i) {
            const int m0 = tm * 128 + wm + i * 16 + quad * 4;
#pragma unroll
            for (int j = 0; j < 4; ++j) {
                const int n = tn * 128 + wn + j * 16 + l16;
                const float bv = bias[n];
#pragma unroll
                for (int r = 0; r < 4; ++r)
                    C[(long long)(m0 + r) * N + n] = f2bf(acc[i][j][r] + bv);
            }
        }
    } else { // MODE 1: transposed bf16 store through LDS (v-proj only)
        const int batch_o = (tm * 128) >> 11;
        const int s0 = (tm * 128) & 2047;
        unsigned short* out = (unsigned short*)Cv + (long long)batch_o * 2097152LL + s0;
        const int STR = 132;
#pragma unroll
        for (int c = 0; c < 4; ++c) {
            __syncthreads();
            if ((wn >> 6) == (c >> 1)) {
                const int jbase = (c & 1) * 2;
#pragma unroll
                for (int jj = 0; jj < 2; ++jj) {
                    const int j = jbase + jj;
                    const int nnl = j * 16 + l16 - (c & 1) * 32;
                    const float bv = bias[tn * 128 + wn + j * 16 + l16];
#pragma unroll
                    for (int i = 0; i < 4; ++i) {
                        const int mmb = wm + i * 16 + quad * 4;
#pragma unroll
                        for (int r = 0; r < 4; ++r)
                            sh[nnl * STR + mmb + r] = f2bf(acc[i][j][r] + bv);
                    }
                }
            }
            __syncthreads();
#pragma unroll
            for (int rr = 0; rr < 4; ++rr) {
                const int row = rr * 8 + (tid >> 5);
                const int cs = (tid & 31) * 4;
                unsigned long long v8 = *(const unsigned long long*)&sh[row * STR + cs];
                *(unsigned long long*)&out[(long long)(tn * 128 + c * 32 + row) * 2048 + cs] = v8;
            }
        }
    }
}

extern "C" void kernel_launch(void* const* d_in, const int* in_sizes, int n_in,
                              void* d_out, int out_size, void* d_ws, size_t ws_size,
                              hipStream_t stream) {
    const float* query = (const float*)d_in[0];   // [16,2048,1024]
    const float* key   = (const float*)d_in[1];   // [16,2048,768]
    const float* value = (const float*)d_in[2];   // [16,2048,768]
    const float* Wq    = (const float*)d_in[3];   // [1024,1024]
    const float* bq    = (const float*)d_in[4];
    const float* Wk    = (const float*)d_in[5];   // [1024,768]
    const float* bk    = (const float*)d_in[6];
    const float* Wv    = (const float*)d_in[7];   // [1024,768]
    const float* bv    = (const float*)d_in[8];

    char* ws = (char*)d_ws;
    unsigned short* qin = (unsigned short*)ws;                    // 33,554,432 elems
    unsigned short* kin = qin + 33554432LL;                       // 25,165,824
    unsigned short* vin = kin + 25165824LL;                       // 25,165,824
    unsigned short* Sb  = (unsigned short*)ws;                    // alias (after projections)
    float* rowsum = (float*)(ws + 134217728LL);                   // 32768 f32
    unsigned short* Wqb = (unsigned short*)(ws + 167772160LL);    // 1,048,576
    unsigned short* Wkb = Wqb + 1048576LL;                        // 786,432
    unsigned short* Wvb = Wkb + 786432LL;                         // 786,432
    unsigned short* qp  = (unsigned short*)(ws + 173015040LL);    // 33,554,432
    unsigned short* kp  = qp + 33554432LL;                        // 33,554,432
    unsigned short* vT  = kp + 33554432LL;                        // 33,554,432 ([16][1024][2048])

    dim3 blk(256);
    dim3 blk2(512);

    // 1) converts
    cvt3<<<8192, blk, 0, stream>>>(query, qin, 33554432 / 4,
                                   key,   kin, 25165824 / 4,
                                   value, vin, 25165824 / 4);
    cvt3<<<2560, blk, 0, stream>>>(Wq, Wqb, 1048576 / 4,
                                   Wk, Wkb, 786432 / 4,
                                   Wv, Wvb, 786432 / 4);

    // 2) projections (q,k on 256^2 pipeline; v keeps fused transpose epilogue)
    gemm256<0><<<dim3(512, 1), blk2, 0, stream>>>(qin, Wqb, qp, bq, nullptr, nullptr, 0.f,
                                                  32768, 1024, 1024, 0, 0, 0);
    gemm256<0><<<dim3(512, 1), blk2, 0, stream>>>(kin, Wkb, kp, bk, nullptr, nullptr, 0.f,
                                                  32768, 1024, 768, 0, 0, 0);
    gemm_bt<1><<<dim3(2048, 1), blk, 0, stream>>>(vin, Wvb, vT, bv, nullptr, nullptr, 0.f,
                                                  32768, 1024, 768, 0, 0, 0);

    // 3) zero row sums
    hipMemsetAsync(rowsum, 0, 32768 * sizeof(float), stream);

    // 4) S~ = exp(q.k^T * scale), bf16, + row sums  (batched x16)
    gemm256<2><<<dim3(64, 16), blk2, 0, stream>>>(qp, kp, Sb, nullptr, rowsum, nullptr, 0.03125f,
                                                  2048, 2048, 1024, 2097152LL, 2097152LL, 4194304LL);

    // 5) rowsum -> 1/rowsum
    recip_k<<<128, blk, 0, stream>>>(rowsum, 32768);

    // 6) O = (S~ . vT) * rowinv  (batched x16), fp32 out
    gemm256<3><<<dim3(32, 16), blk2, 0, stream>>>(Sb, vT, (float*)d_out, nullptr, nullptr, rowsum, 1.0f,
                                                  2048, 1024, 2048, 4194304LL, 2097152LL, 2097152LL);
}

// Round 3
// 923.962 us; speedup vs baseline: 1.2286x; 1.0413x over previous
//
#include <hip/hip_runtime.h>
#include <hip/hip_bf16.h>
#include <stdint.h>

typedef __attribute__((ext_vector_type(8))) short s16x8;
typedef __attribute__((ext_vector_type(4))) float f32x4;

__device__ __forceinline__ unsigned short f2bf(float f) {
    unsigned int u = __float_as_uint(f);
    u += 0x7fffu + ((u >> 16) & 1u);   // round-to-nearest-even
    return (unsigned short)(u >> 16);
}

__device__ __forceinline__ void load16_lds(const unsigned short* g, unsigned short* l) {
    __builtin_amdgcn_global_load_lds(
        (const __attribute__((address_space(1))) unsigned int*)g,
        (__attribute__((address_space(3))) unsigned int*)l,
        16, 0, 0);
}

// ---------------- fused fp32 -> bf16 convert over 3 arrays (float4 units) ----------------
__global__ __launch_bounds__(256) void cvt3(
    const float* __restrict__ a, unsigned short* __restrict__ da, int na,
    const float* __restrict__ b, unsigned short* __restrict__ db, int nb,
    const float* __restrict__ c, unsigned short* __restrict__ dc, int nc)
{
    const int total = na + nb + nc;
    for (int i = blockIdx.x * 256 + threadIdx.x; i < total; i += gridDim.x * 256) {
        const float* s; unsigned short* d; int j = i;
        if (j < na)            { s = a; d = da; }
        else if (j < na + nb)  { s = b; d = db; j -= na; }
        else                   { s = c; d = dc; j -= na + nb; }
        float4 v = ((const float4*)s)[j];
        ushort4 o;
        o.x = f2bf(v.x); o.y = f2bf(v.y); o.z = f2bf(v.z); o.w = f2bf(v.w);
        ((ushort4*)d)[j] = o;
    }
}

__global__ __launch_bounds__(256) void recip_k(float* __restrict__ p, int n) {
    int i = blockIdx.x * 256 + threadIdx.x;
    if (i < n) p[i] = 1.0f / p[i];
}

// =====================================================================================
// 256x256 tile, 512 threads = 8 waves (2M x 4N). K consumed in 32-wide K-halves (KH).
// 4-slot LDS ring (4 x 32KB = 128KB), 3-deep prefetch, counted s_waitcnt vmcnt(8).
// NEW (r3): each KH split into TWO sub-phases (16-MFMA clusters) with reads/stages
// interleaved per sub-phase and a mid-KH barrier (T3 fine interleave; T5 setprio pays).
// XCD-aware bijective tile swizzle for MODE 2/3 (T1).
//
// vmcnt ledger (per thread, 4 loads per KH, split 2+2 across sub-phases):
//   At KH j sp0 wait: outstanding = KH j (4) + KH j+1 (4) + KH j+2 (4) = 12.
//   vmcnt(8) retires exactly KH j. Tail: j+2==NKH -> vmcnt(4); j+1==NKH -> vmcnt(0).
//   Staging into slot (j+3)&3 == (j-1)&3 is issued only after a barrier that
//   postdates every wave's last ds_read of that slot (phase j-1 sp1) -> race-free.
// =====================================================================================
template <int MODE>
__global__ __launch_bounds__(512, 2) void gemm256(
    const unsigned short* __restrict__ A, const unsigned short* __restrict__ B,
    void* __restrict__ Cv, const float* __restrict__ bias,
    float* __restrict__ rowsum, const float* __restrict__ rowinv, float scale,
    int M, int N, int K,
    long long strideA, long long strideB, long long strideC)
{
    // 4 KH slots: each slot = A[256][32] (8192 sh) + B[256][32] (8192 sh) = 32 KiB
    __shared__ unsigned short sh[65536];   // 128 KiB

    const int batch = blockIdx.y;
    A += (long long)batch * strideA;
    B += (long long)batch * strideB;

    // tile coordinates; XCD-aware bijective swizzle for the batched attention GEMMs.
    // Linear block id = x + gridDim.x*y; gridDim.x % 8 == 0 so xcd = x & 7.
    int tm, tn;
    if (MODE == 2) {                       // 8x8 tiles: 2x4 rectangle per XCD (~3MB/XCD)
        const int xcd = blockIdx.x & 7, idx = blockIdx.x >> 3;   // idx 0..7
        tm = 2 * (xcd >> 1) + (idx >> 2);
        tn = 4 * (xcd & 1) + (idx & 3);
    } else if (MODE == 3) {                // 8x4 tiles: 2x2 rectangle per XCD
        const int xcd = blockIdx.x & 7, idx = blockIdx.x >> 3;   // idx 0..3
        tm = 2 * (xcd >> 1) + (idx >> 1);
        tn = 2 * (xcd & 1) + (idx & 1);
    } else {
        const int ntn = N >> 8;
        tm = blockIdx.x / ntn;
        tn = blockIdx.x % ntn;
    }

    const int tid  = threadIdx.x;
    const int wave = tid >> 6;
    const int lane = tid & 63;
    const int quad = lane >> 4;
    const int l16  = lane & 15;
    const int wm   = wave >> 2;    // 0..1 (M half)
    const int wn   = wave & 3;     // 0..3 (N quarter)

    // staging: per KH, 4 units [A-lo, A-hi, B-lo, B-hi], each [128][32] row-major.
    const int srow = (wave << 4) + (lane >> 2);          // 0..127
    const int scol = (lane & 3) << 3;                    // 0,8,16,24
    const unsigned short* gA0 = A + (long long)(tm * 256 +       srow) * K + scol;
    const unsigned short* gA1 = A + (long long)(tm * 256 + 128 + srow) * K + scol;
    const unsigned short* gB0 = B + (long long)(tn * 256 +       srow) * K + scol;
    const unsigned short* gB1 = B + (long long)(tn * 256 + 128 + srow) * K + scol;
    const int sdst = wave * 512;                         // wave-uniform short offset in unit

    const int NKH = K >> 5;                              // 32-wide K-halves (>= 24 here)

    // fragment read offsets (shorts), slot-relative; contiguous 1024B per wave-read.
    const int aoff =        wm * 4096 + l16 * 32 + quad * 8;
    const int boff = 8192 + wn * 2048 + l16 * 32 + quad * 8;

    f32x4 acc[8][4] = {};

    // prologue: stage KH 0,1,2
    for (int p = 0; p < 3; ++p) {
        unsigned short* sb = sh + p * 16384;
        const int kof = p * 32;
        load16_lds(gA0 + kof, sb +         sdst);
        load16_lds(gA1 + kof, sb +  4096 + sdst);
        load16_lds(gB0 + kof, sb +  8192 + sdst);
        load16_lds(gB1 + kof, sb + 12288 + sdst);
    }

    for (int j = 0; j < NKH; ++j) {
        const unsigned short* sa  = sh + (j & 3) * 16384 + aoff;
        const unsigned short* sbb = sh + (j & 3) * 16384 + boff;
        unsigned short* stg = sh + ((j + 3) & 3) * 16384;
        const int kof = (j + 3) * 32;
        const bool do_stage = (j + 3 < NKH);

        // ---------------- sub-phase 0: B0-3 + A0-3 reads, 2 stage loads, 16 MFMA ----
        __builtin_amdgcn_sched_barrier(0);
        if (j + 3 <= NKH)      { asm volatile("s_waitcnt vmcnt(8)" ::: "memory"); }
        else if (j + 2 == NKH) { asm volatile("s_waitcnt vmcnt(4)" ::: "memory"); }
        else                   { asm volatile("s_waitcnt vmcnt(0)" ::: "memory"); }
        __builtin_amdgcn_s_barrier();        // all waves' KH-j loads retired past here
        __builtin_amdgcn_sched_barrier(0);

        s16x8 bfr[4], af0[4];
#pragma unroll
        for (int n = 0; n < 4; ++n) bfr[n] = *(const s16x8*)(sbb + n * 512);
#pragma unroll
        for (int m = 0; m < 4; ++m) af0[m] = *(const s16x8*)(sa + m * 512);
        if (do_stage) {
            load16_lds(gA0 + kof, stg +        sdst);
            load16_lds(gA1 + kof, stg + 4096 + sdst);
        }
        asm volatile("s_waitcnt lgkmcnt(0)" ::: "memory");
        __builtin_amdgcn_sched_barrier(0);
        __builtin_amdgcn_s_setprio(1);
#pragma unroll
        for (int m = 0; m < 4; ++m)
#pragma unroll
            for (int n = 0; n < 4; ++n)
                acc[m][n] = __builtin_amdgcn_mfma_f32_16x16x32_bf16(af0[m], bfr[n], acc[m][n], 0, 0, 0);
        __builtin_amdgcn_s_setprio(0);

        // ---------------- sub-phase 1: A4-7 reads, 2 stage loads, 16 MFMA ------------
        __builtin_amdgcn_sched_barrier(0);
        __builtin_amdgcn_s_barrier();        // stagger fence (role-split for setprio)
        __builtin_amdgcn_sched_barrier(0);

        s16x8 af1[4];
#pragma unroll
        for (int m = 0; m < 4; ++m) af1[m] = *(const s16x8*)(sa + (4 + m) * 512);
        if (do_stage) {
            load16_lds(gB0 + kof, stg +  8192 + sdst);
            load16_lds(gB1 + kof, stg + 12288 + sdst);
        }
        asm volatile("s_waitcnt lgkmcnt(0)" ::: "memory");
        __builtin_amdgcn_sched_barrier(0);
        __builtin_amdgcn_s_setprio(1);
#pragma unroll
        for (int m = 0; m < 4; ++m)
#pragma unroll
            for (int n = 0; n < 4; ++n)
                acc[4 + m][n] = __builtin_amdgcn_mfma_f32_16x16x32_bf16(af1[m], bfr[n], acc[4 + m][n], 0, 0, 0);
        __builtin_amdgcn_s_setprio(0);
    }
    // last KH waited vmcnt(0); lgkm drained per-cluster: clean entering the epilogue.

    // C/D layout: col = l16, row = quad*4 + reg
    if (MODE == 0) {
        unsigned short* C = (unsigned short*)Cv + (long long)batch * strideC;
#pragma unroll
        for (int m = 0; m < 8; ++m) {
            const int m0 = tm * 256 + wm * 128 + m * 16 + quad * 4;
#pragma unroll
            for (int n = 0; n < 4; ++n) {
                const int c = tn * 256 + wn * 64 + n * 16 + l16;
                const float bv = bias[c];
#pragma unroll
                for (int r = 0; r < 4; ++r)
                    C[(long long)(m0 + r) * N + c] = f2bf(acc[m][n][r] + bv);
            }
        }
    } else if (MODE == 2) {
        unsigned short* C = (unsigned short*)Cv + (long long)batch * strideC;
        float psum[8][4];
#pragma unroll
        for (int m = 0; m < 8; ++m)
#pragma unroll
            for (int r = 0; r < 4; ++r) psum[m][r] = 0.0f;
#pragma unroll
        for (int m = 0; m < 8; ++m) {
            const int m0 = tm * 256 + wm * 128 + m * 16 + quad * 4;
#pragma unroll
            for (int n = 0; n < 4; ++n) {
                const int c = tn * 256 + wn * 64 + n * 16 + l16;
#pragma unroll
                for (int r = 0; r < 4; ++r) {
                    float e = __expf(acc[m][n][r] * scale);
                    C[(long long)(m0 + r) * N + c] = f2bf(e);
                    psum[m][r] += e;
                }
            }
        }
        float* rs = rowsum + (long long)batch * 2048;
#pragma unroll
        for (int m = 0; m < 8; ++m) {
            const int m0 = tm * 256 + wm * 128 + m * 16 + quad * 4;
#pragma unroll
            for (int r = 0; r < 4; ++r) {
                float v = psum[m][r];
                v += __shfl_xor(v, 1);
                v += __shfl_xor(v, 2);
                v += __shfl_xor(v, 4);
                v += __shfl_xor(v, 8);
                if (l16 == 0) atomicAdd(&rs[m0 + r], v);
            }
        }
    } else { // MODE 3
        float* C = (float*)Cv + (long long)batch * strideC;
        const float* ri = rowinv + (long long)batch * 2048;
#pragma unroll
        for (int m = 0; m < 8; ++m) {
            const int m0 = tm * 256 + wm * 128 + m * 16 + quad * 4;
            const float4 inv4 = *(const float4*)&ri[m0];
#pragma unroll
            for (int n = 0; n < 4; ++n) {
                const int c = tn * 256 + wn * 64 + n * 16 + l16;
                C[(long long)(m0 + 0) * N + c] = acc[m][n][0] * inv4.x;
                C[(long long)(m0 + 1) * N + c] = acc[m][n][1] * inv4.y;
                C[(long long)(m0 + 2) * N + c] = acc[m][n][2] * inv4.z;
                C[(long long)(m0 + 3) * N + c] = acc[m][n][3] * inv4.w;
            }
        }
    }
}

// ---------------- OLD 128x128 kernel, retained ONLY for the fused v-proj transpose ----
template <int MODE>
__global__ __launch_bounds__(256) void gemm_bt(
    const unsigned short* __restrict__ A, const unsigned short* __restrict__ B,
    void* __restrict__ Cv, const float* __restrict__ bias,
    float* __restrict__ rowsum, const float* __restrict__ rowinv, float scale,
    int M, int N, int K,
    long long strideA, long long strideB, long long strideC)
{
    __shared__ unsigned short sh[8192];       // 16 KB: lA (4096) + lB (4096)
    unsigned short* lA = sh;
    unsigned short* lB = sh + 4096;

    const int batch = blockIdx.y;
    A += (long long)batch * strideA;
    B += (long long)batch * strideB;

    const int ntn = N >> 7;
    const int tm = blockIdx.x / ntn;
    const int tn = blockIdx.x % ntn;

    const int tid = threadIdx.x;
    const int wave = tid >> 6;
    const int lane = tid & 63;
    const int quad = lane >> 4;
    const int l16 = lane & 15;

    const int col = (lane & 3) * 8;
    const int idx0 = (wave * 2 + 0) * 64 + lane;
    const int idx1 = (wave * 2 + 1) * 64 + lane;
    const unsigned short* gA0 = A + (long long)(tm * 128 + (idx0 >> 2)) * K + col;
    const unsigned short* gA1 = A + (long long)(tm * 128 + (idx1 >> 2)) * K + col;
    const unsigned short* gB0 = B + (long long)(tn * 128 + (idx0 >> 2)) * K + col;
    const unsigned short* gB1 = B + (long long)(tn * 128 + (idx1 >> 2)) * K + col;
    unsigned short* dA0 = lA + (wave * 2 + 0) * 512;
    unsigned short* dA1 = lA + (wave * 2 + 1) * 512;
    unsigned short* dB0 = lB + (wave * 2 + 0) * 512;
    unsigned short* dB1 = lB + (wave * 2 + 1) * 512;

    const int wm = (wave >> 1) * 64;
    const int wn = (wave & 1) * 64;

    f32x4 acc[4][4] = {};

    for (int k0 = 0; k0 < K; k0 += 32) {
        __syncthreads();
        load16_lds(gA0, dA0);
        load16_lds(gA1, dA1);
        load16_lds(gB0, dB0);
        load16_lds(gB1, dB1);
        gA0 += 32; gA1 += 32; gB0 += 32; gB1 += 32;
        __syncthreads();

        s16x8 af[4], bfr[4];
#pragma unroll
        for (int i = 0; i < 4; ++i)
            af[i] = *(const s16x8*)&lA[(wm + i * 16 + l16) * 32 + quad * 8];
#pragma unroll
        for (int j = 0; j < 4; ++j)
            bfr[j] = *(const s16x8*)&lB[(wn + j * 16 + l16) * 32 + quad * 8];
#pragma unroll
        for (int i = 0; i < 4; ++i)
#pragma unroll
            for (int j = 0; j < 4; ++j)
                acc[i][j] = __builtin_amdgcn_mfma_f32_16x16x32_bf16(af[i], bfr[j], acc[i][j], 0, 0, 0);
    }

    if (MODE == 0) {
        unsigned short* C = (unsigned short*)Cv + (long long)batch * strideC;
#pragma unroll
        for (int i = 0; i < 4; ++i) {
            const int m0 = tm * 128 + wm + i * 16 + quad * 4;
#pragma unroll
            for (int j = 0; j < 4; ++j) {
                const int n = tn * 128 + wn + j * 16 + l16;
                const float bv = bias[n];
#pragma unroll
                for (int r = 0; r < 4; ++r)
                    C[(long long)(m0 + r) * N + n] = f2bf(acc[i][j][r] + bv);
            }
        }
    } else { // MODE 1: transposed bf16 store through LDS (v-proj only)
        const int batch_o = (tm * 128) >> 11;
        const int s0 = (tm * 128) & 2047;
        unsigned short* out = (unsigned short*)Cv + (long long)batch_o * 2097152LL + s0;
        const int STR = 132;
#pragma unroll
        for (int c = 0; c < 4; ++c) {
            __syncthreads();
            if ((wn >> 6) == (c >> 1)) {
                const int jbase = (c & 1) * 2;
#pragma unroll
                for (int jj = 0; jj < 2; ++jj) {
                    const int j = jbase + jj;
                    const int nnl = j * 16 + l16 - (c & 1) * 32;
                    const float bv = bias[tn * 128 + wn + j * 16 + l16];
#pragma unroll
                    for (int i = 0; i < 4; ++i) {
                        const int mmb = wm + i * 16 + quad * 4;
#pragma unroll
                        for (int r = 0; r < 4; ++r)
                            sh[nnl * STR + mmb + r] = f2bf(acc[i][j][r] + bv);
                    }
                }
            }
            __syncthreads();
#pragma unroll
            for (int rr = 0; rr < 4; ++rr) {
                const int row = rr * 8 + (tid >> 5);
                const int cs = (tid & 31) * 4;
                unsigned long long v8 = *(const unsigned long long*)&sh[row * STR + cs];
                *(unsigned long long*)&out[(long long)(tn * 128 + c * 32 + row) * 2048 + cs] = v8;
            }
        }
    }
}

extern "C" void kernel_launch(void* const* d_in, const int* in_sizes, int n_in,
                              void* d_out, int out_size, void* d_ws, size_t ws_size,
                              hipStream_t stream) {
    const float* query = (const float*)d_in[0];   // [16,2048,1024]
    const float* key   = (const float*)d_in[1];   // [16,2048,768]
    const float* value = (const float*)d_in[2];   // [16,2048,768]
    const float* Wq    = (const float*)d_in[3];   // [1024,1024]
    const float* bq    = (const float*)d_in[4];
    const float* Wk    = (const float*)d_in[5];   // [1024,768]
    const float* bk    = (const float*)d_in[6];
    const float* Wv    = (const float*)d_in[7];   // [1024,768]
    const float* bv    = (const float*)d_in[8];

    char* ws = (char*)d_ws;
    unsigned short* qin = (unsigned short*)ws;                    // 33,554,432 elems
    unsigned short* kin = qin + 33554432LL;                       // 25,165,824
    unsigned short* vin = kin + 25165824LL;                       // 25,165,824
    unsigned short* Sb  = (unsigned short*)ws;                    // alias (after projections)
    float* rowsum = (float*)(ws + 134217728LL);                   // 32768 f32
    unsigned short* Wqb = (unsigned short*)(ws + 167772160LL);    // 1,048,576
    unsigned short* Wkb = Wqb + 1048576LL;                        // 786,432
    unsigned short* Wvb = Wkb + 786432LL;                         // 786,432
    unsigned short* qp  = (unsigned short*)(ws + 173015040LL);    // 33,554,432
    unsigned short* kp  = qp + 33554432LL;                        // 33,554,432
    unsigned short* vT  = kp + 33554432LL;                        // 33,554,432 ([16][1024][2048])

    dim3 blk(256);
    dim3 blk2(512);

    // 1) converts
    cvt3<<<8192, blk, 0, stream>>>(query, qin, 33554432 / 4,
                                   key,   kin, 25165824 / 4,
                                   value, vin, 25165824 / 4);
    cvt3<<<2560, blk, 0, stream>>>(Wq, Wqb, 1048576 / 4,
                                   Wk, Wkb, 786432 / 4,
                                   Wv, Wvb, 786432 / 4);

    // 2) projections (q,k on 256^2 pipeline; v keeps fused transpose epilogue)
    gemm256<0><<<dim3(512, 1), blk2, 0, stream>>>(qin, Wqb, qp, bq, nullptr, nullptr, 0.f,
                                                  32768, 1024, 1024, 0, 0, 0);
    gemm256<0><<<dim3(512, 1), blk2, 0, stream>>>(kin, Wkb, kp, bk, nullptr, nullptr, 0.f,
                                                  32768, 1024, 768, 0, 0, 0);
    gemm_bt<1><<<dim3(2048, 1), blk, 0, stream>>>(vin, Wvb, vT, bv, nullptr, nullptr, 0.f,
                                                  32768, 1024, 768, 0, 0, 0);

    // 3) zero row sums
    hipMemsetAsync(rowsum, 0, 32768 * sizeof(float), stream);

    // 4) S~ = exp(q.k^T * scale), bf16, + row sums  (batched x16)
    gemm256<2><<<dim3(64, 16), blk2, 0, stream>>>(qp, kp, Sb, nullptr, rowsum, nullptr, 0.03125f,
                                                  2048, 2048, 1024, 2097152LL, 2097152LL, 4194304LL);

    // 5) rowsum -> 1/rowsum
    recip_k<<<128, blk, 0, stream>>>(rowsum, 32768);

    // 6) O = (S~ . vT) * rowinv  (batched x16), fp32 out
    gemm256<3><<<dim3(32, 16), blk2, 0, stream>>>(Sb, vT, (float*)d_out, nullptr, nullptr, rowsum, 1.0f,
                                                  2048, 1024, 2048, 4194304LL, 2097152LL, 2097152LL);
}